// Round 5
// baseline (294.638 us; speedup 1.0000x reference)
//
#include <hip/hip_runtime.h>
#include <hip/hip_bf16.h>
#include <stdint.h>

// Problem constants (fixed by the reference)
#define NN    20000      // nodes
#define NP    20096      // nodes padded to 157*128 (garbage rows never read back)
#define EE    320000     // edges (w/o self loops)
#define CH    128        // feature width per gate
#define GC    512        // 4 gates * 128
#define NHtot 2560000    // N*CH

typedef short bf16x8 __attribute__((ext_vector_type(8)));   // 8 bf16 (4 VGPRs)
typedef float f32x4  __attribute__((ext_vector_type(4)));   // 4 fp32 acc

// ---------- bf16 helpers ----------
__device__ __forceinline__ float bf2f(unsigned short u) {
    union { unsigned int i; float f; } c; c.i = ((unsigned int)u) << 16; return c.f;
}
__device__ __forceinline__ unsigned short f2bf(float f) {
    __hip_bfloat16 b = __float2bfloat16(f);           // RNE
    union { __hip_bfloat16 b; unsigned short u; } c; c.b = b; return c.u;
}
__device__ __forceinline__ void unpack4(uint2 v, float* f) {
    f[0] = bf2f((unsigned short)(v.x & 0xffff)); f[1] = bf2f((unsigned short)(v.x >> 16));
    f[2] = bf2f((unsigned short)(v.y & 0xffff)); f[3] = bf2f((unsigned short)(v.y >> 16));
}
__device__ __forceinline__ uint2 pack4(const float* f) {
    uint2 v;
    v.x = (unsigned int)f2bf(f[0]) | ((unsigned int)f2bf(f[1]) << 16);
    v.y = (unsigned int)f2bf(f[2]) | ((unsigned int)f2bf(f[3]) << 16);
    return v;
}

// ---------- 1. degree + in-edge count (atomics over E) ----------
__global__ void k_count(const int* __restrict__ ei, const float* __restrict__ ew,
                        float* __restrict__ deg, int* __restrict__ cnt) {
    int e = blockIdx.x * 256 + threadIdx.x;
    if (e >= EE) return;
    int d = ei[EE + e];                 // dst row
    atomicAdd(&deg[d], ew[e]);
    atomicAdd(&cnt[d], 1);
}

// ---------- 2. dis = rsqrt(deg + 1) ----------
__global__ void k_dis(float* __restrict__ deg) {
    int i = blockIdx.x * 256 + threadIdx.x;
    if (i >= NN) return;
    float dv = deg[i] + 1.0f;
    deg[i] = rsqrtf(fmaxf(dv, 1e-12f));   // in-place: buffer becomes `dis`
}

// ---------- 3. hierarchical exclusive scan of counts ----------
__global__ void k_scan1(const int* __restrict__ cnt, int* __restrict__ rowoff,
                        int* __restrict__ bsum) {
    __shared__ int wsum[4];
    int i = blockIdx.x * 256 + threadIdx.x;
    int self = (i < NN) ? cnt[i] : 0;
    int lane = threadIdx.x & 63, wid = threadIdx.x >> 6;
    int v = self;
    #pragma unroll
    for (int off = 1; off < 64; off <<= 1) {
        int u = __shfl_up(v, off);
        if (lane >= off) v += u;
    }
    if (lane == 63) wsum[wid] = v;
    __syncthreads();
    int wof = 0;
    for (int k = 0; k < wid; ++k) wof += wsum[k];
    if (i < NN) rowoff[i] = wof + v - self;
    if (threadIdx.x == 255) bsum[blockIdx.x] = wof + v;
}

__global__ void k_scan2(int* __restrict__ bsum) {
    int lane = threadIdx.x;                          // 64 threads
    int base = 0;
    for (int start = 0; start < 80; start += 64) {
        int i = start + lane;
        int self = (i < 80) ? bsum[i] : 0;
        int v = self;
        #pragma unroll
        for (int off = 1; off < 64; off <<= 1) {
            int u = __shfl_up(v, off);
            if (lane >= off) v += u;
        }
        if (i < 80) bsum[i] = base + v - self;
        base += __shfl(v, 63);
    }
}

__global__ void k_scan3(int* __restrict__ rowoff, const int* __restrict__ bsum,
                        int* __restrict__ cur) {
    int i = blockIdx.x * 256 + threadIdx.x;
    if (i < NN) {
        int v = rowoff[i] + bsum[i >> 8];
        rowoff[i] = v; cur[i] = v;
    }
    if (i == NN) rowoff[NN] = EE;
}

// ---------- 4. scatter edges into CSR with precomputed sym-norm weight ----------
__global__ void k_scatter(const int* __restrict__ ei, const float* __restrict__ ew,
                          const float* __restrict__ dis, int* __restrict__ cur,
                          int* __restrict__ csrs, float* __restrict__ csrn) {
    int e = blockIdx.x * 256 + threadIdx.x;
    if (e >= EE) return;
    int s = ei[e], d = ei[EE + e];
    float nrm = dis[s] * ew[e] * dis[d];
    int p = atomicAdd(&cur[d], 1);
    csrs[p] = s; csrn[p] = nrm;
}

// ---------- 5a. cast & pack x|h into [N][256] bf16 ----------
__global__ void k_castxh(const float* __restrict__ x, const float* __restrict__ h,
                         unsigned short* __restrict__ xhb) {
    int idx = blockIdx.x * 256 + threadIdx.x;        // 0 .. NN*32-1 (exact grid)
    int n = idx >> 5, c4 = idx & 31;
    float4 xv = *(const float4*)(x + (size_t)n * CH + c4 * 4);
    float4 hv = *(const float4*)(h + (size_t)n * CH + c4 * 4);
    float fx[4] = { xv.x, xv.y, xv.z, xv.w };
    float fh[4] = { hv.x, hv.y, hv.z, hv.w };
    *(uint2*)(xhb + (size_t)n * 256 + c4 * 4)       = pack4(fx);
    *(uint2*)(xhb + (size_t)n * 256 + 128 + c4 * 4) = pack4(fh);
}

// ---------- 5b. fused prop over packed 256-wide bf16 rows, 2 feature slices ----------
// slice = blockIdx.x & 1 -> XCD-affine under round-robin dispatch; per-slice
// table = 5.15 MB, mostly L2-resident. 1 dword/lane, 4-edge unroll for MLP.
__global__ __launch_bounds__(128) void k_prop256(
        const unsigned short* __restrict__ tab, unsigned short* __restrict__ o,
        const int* __restrict__ rowoff, const int* __restrict__ csrs,
        const float* __restrict__ csrn, const float* __restrict__ dis) {
    int bid   = blockIdx.x;                          // grid = (NN/2)*2
    int slice = bid & 1;
    int w     = (bid >> 1) * 2 + (threadIdx.x >> 6);
    int lane  = threadIdx.x & 63;
    const unsigned int* T1 = (const unsigned int*)tab;   // row = 128 dwords
    size_t boff = (size_t)slice * 64 + lane;             // dword offset in row
    float dv = dis[w], sw = dv * dv;
    unsigned int v = T1[(size_t)w * 128 + boff];
    float a0 = sw * bf2f((unsigned short)(v & 0xffff));
    float a1 = sw * bf2f((unsigned short)(v >> 16));
    int e = rowoff[w], e1 = rowoff[w + 1];
    for (; e + 4 <= e1; e += 4) {
        int   s0 = csrs[e],   s1 = csrs[e+1], s2 = csrs[e+2], s3 = csrs[e+3];
        float n0 = csrn[e],   n1 = csrn[e+1], n2 = csrn[e+2], n3 = csrn[e+3];
        unsigned int u0 = T1[(size_t)s0 * 128 + boff];
        unsigned int u1 = T1[(size_t)s1 * 128 + boff];
        unsigned int u2 = T1[(size_t)s2 * 128 + boff];
        unsigned int u3 = T1[(size_t)s3 * 128 + boff];
        a0 += n0 * bf2f((unsigned short)(u0 & 0xffff)) + n1 * bf2f((unsigned short)(u1 & 0xffff))
            + n2 * bf2f((unsigned short)(u2 & 0xffff)) + n3 * bf2f((unsigned short)(u3 & 0xffff));
        a1 += n0 * bf2f((unsigned short)(u0 >> 16)) + n1 * bf2f((unsigned short)(u1 >> 16))
            + n2 * bf2f((unsigned short)(u2 >> 16)) + n3 * bf2f((unsigned short)(u3 >> 16));
    }
    for (; e < e1; ++e) {
        int s = csrs[e]; float nw = csrn[e];
        unsigned int u = T1[(size_t)s * 128 + boff];
        a0 += nw * bf2f((unsigned short)(u & 0xffff));
        a1 += nw * bf2f((unsigned short)(u >> 16));
    }
    unsigned int ov = (unsigned int)f2bf(a0) | ((unsigned int)f2bf(a1) << 16);
    ((unsigned int*)o)[(size_t)w * 128 + boff] = ov;
}

// ---------- 5c. weight prep: fp32 [4][128][128] k-major -> bf16 n-major ----------
__global__ void k_prepw(const float* __restrict__ W0, const float* __restrict__ W1,
                        const float* __restrict__ W2, const float* __restrict__ W3,
                        unsigned short* __restrict__ T0, unsigned short* __restrict__ T1,
                        unsigned short* __restrict__ T2, unsigned short* __restrict__ T3) {
    const float* W; unsigned short* T;
    switch (blockIdx.z) {
        case 0:  W = W0; T = T0; break;
        case 1:  W = W1; T = T1; break;
        case 2:  W = W2; T = T2; break;
        default: W = W3; T = T3; break;
    }
    int g = blockIdx.y;
    int n = blockIdx.x * 2 + (threadIdx.x >> 7);
    int k = threadIdx.x & 127;
    T[((size_t)g * 128 + n) * 128 + k] = f2bf(W[((size_t)g * 128 + k) * 128 + n]);
}

// ---------- MFMA GEMM shared machinery ----------
#define SWZ(r, c8) (((r) << 4) + ((c8) ^ ((r) & 15)))

// ---------- 6. GEMM1: h0 = relu(A @ W0[g] + b0[g]) -> bf16 [NP,512] ----------
// A = packed prop output [NP][256] bf16; aoff selects x-half (0) or h-half (128)
__global__ __launch_bounds__(256) void k_gemm1(
        const unsigned short* __restrict__ A, int aoff,
        const unsigned short* __restrict__ Wt,
        const float* __restrict__ bias, unsigned short* __restrict__ out) {
    __shared__ uint4 As[2048];                       // 32 KB
    __shared__ uint4 Bs[2048];                       // 32 KB
    const int    g    = blockIdx.y;
    const size_t row0 = (size_t)blockIdx.x * 128;
    const int    t    = threadIdx.x;

    #pragma unroll
    for (int p = 0; p < 8; ++p) {                    // stage A 128x128 bf16
        int id = t + 256 * p, r = id >> 4, c8 = id & 15;
        As[SWZ(r, c8)] = *(const uint4*)(A + (row0 + r) * 256 + aoff + c8 * 8);
    }
    const unsigned short* Wg = Wt + (size_t)g * 16384;   // [n][k] bf16
    #pragma unroll
    for (int p = 0; p < 8; ++p) {                    // stage W^T 128x128 bf16
        int id = t + 256 * p, r = id >> 4, c8 = id & 15;
        Bs[SWZ(r, c8)] = *(const uint4*)(Wg + r * CH + c8 * 8);
    }
    __syncthreads();

    const int wid = t >> 6, l = t & 63;
    const int m0 = (wid >> 1) * 64, n0 = (wid & 1) * 64;
    const int lm = l & 15, q = l >> 4;
    f32x4 acc[4][4];
    #pragma unroll
    for (int i = 0; i < 4; ++i)
        #pragma unroll
        for (int j = 0; j < 4; ++j) { acc[i][j][0]=0.f; acc[i][j][1]=0.f; acc[i][j][2]=0.f; acc[i][j][3]=0.f; }

    #pragma unroll
    for (int kc = 0; kc < 4; ++kc) {
        int c8 = kc * 4 + q;
        bf16x8 a[4], b[4];
        #pragma unroll
        for (int i = 0; i < 4; ++i) { int r = m0 + i * 16 + lm; a[i] = *(const bf16x8*)&As[SWZ(r, c8)]; }
        #pragma unroll
        for (int j = 0; j < 4; ++j) { int r = n0 + j * 16 + lm; b[j] = *(const bf16x8*)&Bs[SWZ(r, c8)]; }
        #pragma unroll
        for (int i = 0; i < 4; ++i)
            #pragma unroll
            for (int j = 0; j < 4; ++j)
                acc[i][j] = __builtin_amdgcn_mfma_f32_16x16x32_bf16(a[i], b[j], acc[i][j], 0, 0, 0);
    }

    #pragma unroll
    for (int j = 0; j < 4; ++j) {
        float bb = bias[g * CH + n0 + j * 16 + lm];
        #pragma unroll
        for (int i = 0; i < 4; ++i)
            #pragma unroll
            for (int r = 0; r < 4; ++r) {
                int rowl = m0 + i * 16 + q * 4 + r;   // C/D: row=(lane>>4)*4+reg
                int col  = n0 + j * 16 + lm;          //      col=lane&15
                out[(row0 + rowl) * GC + g * CH + col] = f2bf(fmaxf(acc[i][j][r] + bb, 0.f));
            }
    }
}

// ---------- 7. GEMM2 (fused): S[g] = h0x[g]@Wx1[g] + h0h[g]@Wh1[g] -> bf16 [NP,512] ----------
__global__ __launch_bounds__(256) void k_gemm2(
        const unsigned short* __restrict__ A1, const unsigned short* __restrict__ A2,
        const unsigned short* __restrict__ Wt1, const unsigned short* __restrict__ Wt2,
        unsigned short* __restrict__ outS) {
    __shared__ uint4 As[2048];
    __shared__ uint4 Bs[2048];
    const int    g    = blockIdx.y;
    const size_t row0 = (size_t)blockIdx.x * 128;
    const int    t    = threadIdx.x;
    const int wid = t >> 6, l = t & 63;
    const int m0 = (wid >> 1) * 64, n0 = (wid & 1) * 64;
    const int lm = l & 15, q = l >> 4;
    f32x4 acc[4][4];
    #pragma unroll
    for (int i = 0; i < 4; ++i)
        #pragma unroll
        for (int j = 0; j < 4; ++j) { acc[i][j][0]=0.f; acc[i][j][1]=0.f; acc[i][j][2]=0.f; acc[i][j][3]=0.f; }

    for (int side = 0; side < 2; ++side) {
        if (side) __syncthreads();                   // all waves done reading LDS
        const unsigned short* Ap = side ? A2 : A1;
        const unsigned short* Wg = (side ? Wt2 : Wt1) + (size_t)g * 16384;
        #pragma unroll
        for (int p = 0; p < 8; ++p) {
            int id = t + 256 * p, r = id >> 4, c8 = id & 15;
            As[SWZ(r, c8)] = *(const uint4*)(Ap + (row0 + r) * GC + g * CH + c8 * 8);
        }
        #pragma unroll
        for (int p = 0; p < 8; ++p) {
            int id = t + 256 * p, r = id >> 4, c8 = id & 15;
            Bs[SWZ(r, c8)] = *(const uint4*)(Wg + r * CH + c8 * 8);
        }
        __syncthreads();
        #pragma unroll
        for (int kc = 0; kc < 4; ++kc) {
            int c8 = kc * 4 + q;
            bf16x8 a[4], b[4];
            #pragma unroll
            for (int i = 0; i < 4; ++i) { int r = m0 + i * 16 + lm; a[i] = *(const bf16x8*)&As[SWZ(r, c8)]; }
            #pragma unroll
            for (int j = 0; j < 4; ++j) { int r = n0 + j * 16 + lm; b[j] = *(const bf16x8*)&Bs[SWZ(r, c8)]; }
            #pragma unroll
            for (int i = 0; i < 4; ++i)
                #pragma unroll
                for (int j = 0; j < 4; ++j)
                    acc[i][j] = __builtin_amdgcn_mfma_f32_16x16x32_bf16(a[i], b[j], acc[i][j], 0, 0, 0);
        }
    }

    #pragma unroll
    for (int j = 0; j < 4; ++j)
        #pragma unroll
        for (int i = 0; i < 4; ++i)
            #pragma unroll
            for (int r = 0; r < 4; ++r) {
                int rowl = m0 + i * 16 + q * 4 + r;
                int col  = n0 + j * 16 + lm;
                outS[(row0 + rowl) * GC + g * CH + col] = f2bf(acc[i][j][r]);
            }
}

// ---------- 8. prop over 512-wide bf16, 4 feature slices ----------
// slice = blockIdx.x & 3 -> XCD-affine under round-robin dispatch; per-slice
// table = 5.15 MB vs 4 MB L2/XCD. 1 dword/lane, 4-edge unroll.
__global__ __launch_bounds__(128) void k_prop512(
        const unsigned short* __restrict__ Sb, unsigned short* __restrict__ G0,
        const int* __restrict__ rowoff, const int* __restrict__ csrs,
        const float* __restrict__ csrn, const float* __restrict__ dis) {
    int bid   = blockIdx.x;                          // grid = (NN/2)*4
    int slice = bid & 3;
    int w     = (bid >> 2) * 2 + (threadIdx.x >> 6);
    int lane  = threadIdx.x & 63;
    const unsigned int* S1 = (const unsigned int*)Sb;    // row = 256 dwords
    size_t boff = (size_t)slice * 64 + lane;             // dword offset in row
    float dv = dis[w], sw = dv * dv;
    unsigned int v = S1[(size_t)w * 256 + boff];
    float a0 = sw * bf2f((unsigned short)(v & 0xffff));
    float a1 = sw * bf2f((unsigned short)(v >> 16));
    int e = rowoff[w], e1 = rowoff[w + 1];
    for (; e + 4 <= e1; e += 4) {
        int   s0 = csrs[e],   s1 = csrs[e+1], s2 = csrs[e+2], s3 = csrs[e+3];
        float n0 = csrn[e],   n1 = csrn[e+1], n2 = csrn[e+2], n3 = csrn[e+3];
        unsigned int u0 = S1[(size_t)s0 * 256 + boff];
        unsigned int u1 = S1[(size_t)s1 * 256 + boff];
        unsigned int u2 = S1[(size_t)s2 * 256 + boff];
        unsigned int u3 = S1[(size_t)s3 * 256 + boff];
        a0 += n0 * bf2f((unsigned short)(u0 & 0xffff)) + n1 * bf2f((unsigned short)(u1 & 0xffff))
            + n2 * bf2f((unsigned short)(u2 & 0xffff)) + n3 * bf2f((unsigned short)(u3 & 0xffff));
        a1 += n0 * bf2f((unsigned short)(u0 >> 16)) + n1 * bf2f((unsigned short)(u1 >> 16))
            + n2 * bf2f((unsigned short)(u2 >> 16)) + n3 * bf2f((unsigned short)(u3 >> 16));
    }
    for (; e < e1; ++e) {
        int s = csrs[e]; float nw = csrn[e];
        unsigned int u = S1[(size_t)s * 256 + boff];
        a0 += nw * bf2f((unsigned short)(u & 0xffff));
        a1 += nw * bf2f((unsigned short)(u >> 16));
    }
    unsigned int ov = (unsigned int)f2bf(a0) | ((unsigned int)f2bf(a1) << 16);
    ((unsigned int*)G0)[(size_t)w * 256 + boff] = ov;
}

// ---------- 9. LSTM gate elementwise ----------
__global__ void k_gates(const unsigned short* __restrict__ G0, const float* __restrict__ c,
                        const float* __restrict__ bx1, const float* __restrict__ bh1,
                        const float* __restrict__ wc, const float* __restrict__ bg,
                        float* __restrict__ out) {
    int idx = blockIdx.x * 256 + threadIdx.x;        // < NHtot (exact grid)
    int n = idx >> 7, hh = idx & 127;
    size_t base = (size_t)n * GC + hh;
    float g0 = bf2f(G0[base])       + bx1[hh]       + bh1[hh];
    float g1 = bf2f(G0[base + 128]) + bx1[128 + hh] + bh1[128 + hh];
    float g2 = bf2f(G0[base + 256]) + bx1[256 + hh] + bh1[256 + hh];
    float g3 = bf2f(G0[base + 384]) + bx1[384 + hh] + bh1[384 + hh];
    float cv = c[idx];
    float I  = 1.f / (1.f + expf(-(g0 + wc[hh]       * cv + bg[hh])));
    float F  = 1.f / (1.f + expf(-(g1 + wc[128 + hh] * cv + bg[128 + hh])));
    float T  = tanhf(g2 + bg[256 + hh]);
    float Cn = F * cv + I * T;
    float O  = 1.f / (1.f + expf(-(g3 + wc[256 + hh] * Cn + bg[384 + hh])));
    out[idx]         = O * tanhf(Cn);                // Hn
    out[NHtot + idx] = Cn;                           // Cn
}

extern "C" void kernel_launch(void* const* d_in, const int* in_sizes, int n_in,
                              void* d_out, int out_size, void* d_ws, size_t ws_size,
                              hipStream_t stream) {
    (void)in_sizes; (void)n_in; (void)out_size; (void)ws_size;
    const float* x   = (const float*)d_in[0];
    const int*   ei  = (const int*)d_in[1];
    const float* ew  = (const float*)d_in[2];
    const float* h   = (const float*)d_in[3];
    const float* c   = (const float*)d_in[4];
    const float* Wx0 = (const float*)d_in[5];
    const float* bx0 = (const float*)d_in[6];
    const float* Wx1 = (const float*)d_in[7];
    const float* bx1 = (const float*)d_in[8];
    const float* Wh0 = (const float*)d_in[9];
    const float* bh0 = (const float*)d_in[10];
    const float* Wh1 = (const float*)d_in[11];
    const float* bh1 = (const float*)d_in[12];
    const float* wc  = (const float*)d_in[13];
    const float* bg  = (const float*)d_in[14];
    float* out = (float*)d_out;

    // Workspace layout (float units). Total ~85.7 MB. All uint4-aligned.
    float* wsf  = (float*)d_ws;
    float* deg  = wsf;                                  // [20480] -> becomes dis
    int*   cnt  = (int*)(wsf + 20480);                  // [20480]
    int*   row  = (int*)(wsf + 40960);                  // [20736]
    int*   cur  = (int*)(wsf + 61696);                  // [20480]
    int*   bsum = (int*)(wsf + 82176);                  // [256]
    int*   csrs = (int*)(wsf + 82432);                  // [E]
    float* csrn = wsf + 402432;                         // [E]
    unsigned short* Wt0x = (unsigned short*)(wsf + 722432);   // [4*128*128] bf16 n-major
    unsigned short* Wt0h = (unsigned short*)(wsf + 755200);
    unsigned short* Wt1x = (unsigned short*)(wsf + 787968);
    unsigned short* Wt1h = (unsigned short*)(wsf + 820736);
    unsigned short* xhb  = (unsigned short*)(wsf + 853504);   // [NP*256] bf16 packed x|h
    unsigned short* axh  = (unsigned short*)(wsf + 3425792);  // [NP*256] bf16 packed ax|ah
    unsigned short* h0x  = (unsigned short*)(wsf + 5998080);  // [NP*512] bf16
    unsigned short* h0h  = (unsigned short*)(wsf + 11142656); // [NP*512] bf16
    unsigned short* Sb   = (unsigned short*)(wsf + 16287232); // [NP*512] bf16
    unsigned short* G0   = h0x;                               // alias: h0x dead after GEMM2

    hipMemsetAsync(deg, 0, 2 * 20480 * sizeof(float), stream);  // deg + cnt

    k_count  <<<EE / 256, 256, 0, stream>>>(ei, ew, deg, cnt);
    k_dis    <<<(NN + 255) / 256, 256, 0, stream>>>(deg);
    k_scan1  <<<80, 256, 0, stream>>>(cnt, row, bsum);
    k_scan2  <<<1, 64, 0, stream>>>(bsum);
    k_scan3  <<<80, 256, 0, stream>>>(row, bsum, cur);
    k_scatter<<<EE / 256, 256, 0, stream>>>(ei, ew, deg, cur, csrs, csrn);

    dim3 pw(64, 4, 4);
    k_prepw  <<<pw, 256, 0, stream>>>(Wx0, Wh0, Wx1, Wh1, Wt0x, Wt0h, Wt1x, Wt1h);
    k_castxh <<<NN * 32 / 256, 256, 0, stream>>>(x, h, xhb);

    k_prop256<<<(NN / 2) * 2, 128, 0, stream>>>(xhb, axh, row, csrs, csrn, deg);

    dim3 gg(NP / 128, 4);
    k_gemm1<<<gg, 256, 0, stream>>>(axh, 0,   Wt0x, bx0, h0x);
    k_gemm1<<<gg, 256, 0, stream>>>(axh, 128, Wt0h, bh0, h0h);
    k_gemm2<<<gg, 256, 0, stream>>>(h0x, h0h, Wt1x, Wt1h, Sb);

    k_prop512<<<(NN / 2) * 4, 128, 0, stream>>>(Sb, G0, row, csrs, csrn, deg);
    k_gates  <<<NHtot / 256, 256, 0, stream>>>(G0, c, bx1, bh1, wc, bg, out);
}

// Round 7
// 265.880 us; speedup vs baseline: 1.1082x; 1.1082x over previous
//
#include <hip/hip_runtime.h>
#include <hip/hip_bf16.h>
#include <stdint.h>

// Problem constants (fixed by the reference)
#define NN    20000      // nodes
#define NP    20096      // nodes padded to 157*128 (garbage rows never read back)
#define EE    320000     // edges (w/o self loops)
#define CH    128        // feature width per gate
#define GC    512        // 4 gates * 128
#define NHtot 2560000    // N*CH

typedef short bf16x8 __attribute__((ext_vector_type(8)));   // 8 bf16 (4 VGPRs)
typedef float f32x4  __attribute__((ext_vector_type(4)));   // 4 fp32 acc

// ---------- bf16 helpers ----------
__device__ __forceinline__ float bf2f(unsigned short u) {
    union { unsigned int i; float f; } c; c.i = ((unsigned int)u) << 16; return c.f;
}
__device__ __forceinline__ unsigned short f2bf(float f) {
    __hip_bfloat16 b = __float2bfloat16(f);           // RNE
    union { __hip_bfloat16 b; unsigned short u; } c; c.b = b; return c.u;
}
__device__ __forceinline__ void unpack8(uint4 v, float* f) {
    f[0] = bf2f((unsigned short)(v.x & 0xffff)); f[1] = bf2f((unsigned short)(v.x >> 16));
    f[2] = bf2f((unsigned short)(v.y & 0xffff)); f[3] = bf2f((unsigned short)(v.y >> 16));
    f[4] = bf2f((unsigned short)(v.z & 0xffff)); f[5] = bf2f((unsigned short)(v.z >> 16));
    f[6] = bf2f((unsigned short)(v.w & 0xffff)); f[7] = bf2f((unsigned short)(v.w >> 16));
}
__device__ __forceinline__ void unpack4(uint2 v, float* f) {
    f[0] = bf2f((unsigned short)(v.x & 0xffff)); f[1] = bf2f((unsigned short)(v.x >> 16));
    f[2] = bf2f((unsigned short)(v.y & 0xffff)); f[3] = bf2f((unsigned short)(v.y >> 16));
}
__device__ __forceinline__ uint2 pack4(const float* f) {
    uint2 v;
    v.x = (unsigned int)f2bf(f[0]) | ((unsigned int)f2bf(f[1]) << 16);
    v.y = (unsigned int)f2bf(f[2]) | ((unsigned int)f2bf(f[3]) << 16);
    return v;
}

// ---------- 1. in-edge count only (int atomics over E; no fp32 atomics) ----------
__global__ void k_count(const int* __restrict__ ei, int* __restrict__ cnt) {
    int e = blockIdx.x * 256 + threadIdx.x;
    if (e >= EE) return;
    atomicAdd(&cnt[ei[EE + e]], 1);
}

// ---------- 2. hierarchical exclusive scan of counts ----------
__global__ void k_scan1(const int* __restrict__ cnt, int* __restrict__ rowoff,
                        int* __restrict__ bsum) {
    __shared__ int wsum[4];
    int i = blockIdx.x * 256 + threadIdx.x;
    int self = (i < NN) ? cnt[i] : 0;
    int lane = threadIdx.x & 63, wid = threadIdx.x >> 6;
    int v = self;
    #pragma unroll
    for (int off = 1; off < 64; off <<= 1) {
        int u = __shfl_up(v, off);
        if (lane >= off) v += u;
    }
    if (lane == 63) wsum[wid] = v;
    __syncthreads();
    int wof = 0;
    for (int k = 0; k < wid; ++k) wof += wsum[k];
    if (i < NN) rowoff[i] = wof + v - self;
    if (threadIdx.x == 255) bsum[blockIdx.x] = wof + v;
}

__global__ void k_scan2(int* __restrict__ bsum) {
    int lane = threadIdx.x;                          // 64 threads
    int base = 0;
    for (int start = 0; start < 80; start += 64) {
        int i = start + lane;
        int self = (i < 80) ? bsum[i] : 0;
        int v = self;
        #pragma unroll
        for (int off = 1; off < 64; off <<= 1) {
            int u = __shfl_up(v, off);
            if (lane >= off) v += u;
        }
        if (i < 80) bsum[i] = base + v - self;
        base += __shfl(v, 63);
    }
}

__global__ void k_scan3(int* __restrict__ rowoff, const int* __restrict__ bsum,
                        int* __restrict__ cur) {
    int i = blockIdx.x * 256 + threadIdx.x;
    if (i < NN) {
        int v = rowoff[i] + bsum[i >> 8];
        rowoff[i] = v; cur[i] = v;
    }
    if (i == NN) rowoff[NN] = EE;
}

// ---------- 3. scatter edges into CSR with RAW weights (no dis dependency) ----------
__global__ void k_scatter(const int* __restrict__ ei, const float* __restrict__ ew,
                          int* __restrict__ cur,
                          int* __restrict__ csrs, float* __restrict__ csrw) {
    int e = blockIdx.x * 256 + threadIdx.x;
    if (e >= EE) return;
    int s = ei[e], d = ei[EE + e];
    int p = atomicAdd(&cur[d], 1);
    csrs[p] = s; csrw[p] = ew[e];
}

// ---------- 4. degree by CSR row sum (atomic-free) -> dis = rsqrt(deg+1) ----------
__global__ void k_deg(const int* __restrict__ rowoff, const float* __restrict__ csrw,
                      float* __restrict__ dis) {
    int i = blockIdx.x * 256 + threadIdx.x;
    if (i >= NN) return;
    float s = 1.0f;                                  // self-loop weight
    int e1 = rowoff[i + 1];
    for (int e = rowoff[i]; e < e1; ++e) s += csrw[e];
    dis[i] = rsqrtf(fmaxf(s, 1e-12f));
}

// ---------- 5a. cast & pack dis-scaled x|h into [N][256] bf16 ----------
__global__ void k_castxh(const float* __restrict__ x, const float* __restrict__ h,
                         const float* __restrict__ dis, unsigned short* __restrict__ xhb) {
    int idx = blockIdx.x * 256 + threadIdx.x;        // 0 .. NN*32-1 (exact grid)
    int n = idx >> 5, c4 = idx & 31;
    float dn = dis[n];
    float4 xv = *(const float4*)(x + (size_t)n * CH + c4 * 4);
    float4 hv = *(const float4*)(h + (size_t)n * CH + c4 * 4);
    float fx[4] = { dn * xv.x, dn * xv.y, dn * xv.z, dn * xv.w };
    float fh[4] = { dn * hv.x, dn * hv.y, dn * hv.z, dn * hv.w };
    *(uint2*)(xhb + (size_t)n * 256 + c4 * 4)       = pack4(fx);
    *(uint2*)(xhb + (size_t)n * 256 + 128 + c4 * 4) = pack4(fh);
}

// ---------- 5b. fused prop over packed 256-wide bf16 rows (table pre-scaled) ----------
// axh[w] = dis_w * (sum_e w_e * T[s_e] + T[w]); one wave/node, 8B/lane, 4-edge unroll
__global__ __launch_bounds__(256) void k_prop256(
        const unsigned short* __restrict__ tab, unsigned short* __restrict__ o,
        const int* __restrict__ rowoff, const int* __restrict__ csrs,
        const float* __restrict__ csrw, const float* __restrict__ dis) {
    int w = blockIdx.x * 4 + (threadIdx.x >> 6);     // grid exact: NN/4 blocks
    int lane = threadIdx.x & 63;
    const uint2* T2 = (const uint2*)tab;             // row = 64 uint2 = 512 B
    float acc[4], va[4], vb[4], vc[4], vd[4];
    uint2 v = T2[(size_t)w * 64 + lane];
    unpack4(v, va);
    #pragma unroll
    for (int j = 0; j < 4; ++j) acc[j] = va[j];      // self term (pre-scaled table)
    int e = rowoff[w], e1 = rowoff[w + 1];
    for (; e + 4 <= e1; e += 4) {
        int   s0 = csrs[e],   s1 = csrs[e+1], s2 = csrs[e+2], s3 = csrs[e+3];
        float n0 = csrw[e],   n1 = csrw[e+1], n2 = csrw[e+2], n3 = csrw[e+3];
        uint2 u0 = T2[(size_t)s0 * 64 + lane];
        uint2 u1 = T2[(size_t)s1 * 64 + lane];
        uint2 u2 = T2[(size_t)s2 * 64 + lane];
        uint2 u3 = T2[(size_t)s3 * 64 + lane];
        unpack4(u0, va); unpack4(u1, vb); unpack4(u2, vc); unpack4(u3, vd);
        #pragma unroll
        for (int j = 0; j < 4; ++j)
            acc[j] += n0 * va[j] + n1 * vb[j] + n2 * vc[j] + n3 * vd[j];
    }
    for (; e < e1; ++e) {
        int s = csrs[e]; float nw = csrw[e];
        v = T2[(size_t)s * 64 + lane];
        unpack4(v, va);
        #pragma unroll
        for (int j = 0; j < 4; ++j) acc[j] += nw * va[j];
    }
    float dw = dis[w];
    #pragma unroll
    for (int j = 0; j < 4; ++j) acc[j] *= dw;
    ((uint2*)o)[(size_t)w * 64 + lane] = pack4(acc);
}

// ---------- 5c. weight prep: fp32 [4][128][128] k-major -> bf16 n-major ----------
__global__ void k_prepw(const float* __restrict__ W0, const float* __restrict__ W1,
                        const float* __restrict__ W2, const float* __restrict__ W3,
                        unsigned short* __restrict__ T0, unsigned short* __restrict__ T1,
                        unsigned short* __restrict__ T2, unsigned short* __restrict__ T3) {
    const float* W; unsigned short* T;
    switch (blockIdx.z) {
        case 0:  W = W0; T = T0; break;
        case 1:  W = W1; T = T1; break;
        case 2:  W = W2; T = T2; break;
        default: W = W3; T = T3; break;
    }
    int g = blockIdx.y;
    int n = blockIdx.x * 2 + (threadIdx.x >> 7);
    int k = threadIdx.x & 127;
    T[((size_t)g * 128 + n) * 128 + k] = f2bf(W[((size_t)g * 128 + k) * 128 + n]);
}

// ---------- 5d. combined layer-2 bias: btot[f] = bx1+bh1+bg ----------
__global__ void k_prepb(const float* __restrict__ bx1, const float* __restrict__ bh1,
                        const float* __restrict__ bg, float* __restrict__ btot) {
    int f = blockIdx.x * 256 + threadIdx.x;
    if (f < GC) btot[f] = bx1[f] + bh1[f] + bg[f];
}

// ---------- MFMA GEMM shared machinery ----------
#define SWZ(r, c8) (((r) << 4) + ((c8) ^ ((r) & 15)))

// ---------- 6. GEMM1 (both sides in one launch via blockIdx.z) ----------
// h0 = relu(axh[:, side] @ W0[g] + b0[g]) -> bf16 [NP,512]
__global__ __launch_bounds__(256) void k_gemm1(
        const unsigned short* __restrict__ A,
        const unsigned short* __restrict__ Wtx, const unsigned short* __restrict__ Wth,
        const float* __restrict__ bx0, const float* __restrict__ bh0,
        unsigned short* __restrict__ outx, unsigned short* __restrict__ outh) {
    __shared__ uint4 As[2048];                       // 32 KB
    __shared__ uint4 Bs[2048];                       // 32 KB
    const int side = blockIdx.z;
    const int aoff = side * 128;
    const unsigned short* Wt = side ? Wth : Wtx;
    const float* bias        = side ? bh0 : bx0;
    unsigned short* out      = side ? outh : outx;

    const int    g    = blockIdx.y;
    const size_t row0 = (size_t)blockIdx.x * 128;
    const int    t    = threadIdx.x;

    #pragma unroll
    for (int p = 0; p < 8; ++p) {                    // stage A 128x128 bf16
        int id = t + 256 * p, r = id >> 4, c8 = id & 15;
        As[SWZ(r, c8)] = *(const uint4*)(A + (row0 + r) * 256 + aoff + c8 * 8);
    }
    const unsigned short* Wg = Wt + (size_t)g * 16384;   // [n][k] bf16
    #pragma unroll
    for (int p = 0; p < 8; ++p) {                    // stage W^T 128x128 bf16
        int id = t + 256 * p, r = id >> 4, c8 = id & 15;
        Bs[SWZ(r, c8)] = *(const uint4*)(Wg + r * CH + c8 * 8);
    }
    __syncthreads();

    const int wid = t >> 6, l = t & 63;
    const int m0 = (wid >> 1) * 64, n0 = (wid & 1) * 64;
    const int lm = l & 15, q = l >> 4;
    f32x4 acc[4][4];
    #pragma unroll
    for (int i = 0; i < 4; ++i)
        #pragma unroll
        for (int j = 0; j < 4; ++j) { acc[i][j][0]=0.f; acc[i][j][1]=0.f; acc[i][j][2]=0.f; acc[i][j][3]=0.f; }

    #pragma unroll
    for (int kc = 0; kc < 4; ++kc) {
        int c8 = kc * 4 + q;
        bf16x8 a[4], b[4];
        #pragma unroll
        for (int i = 0; i < 4; ++i) { int r = m0 + i * 16 + lm; a[i] = *(const bf16x8*)&As[SWZ(r, c8)]; }
        #pragma unroll
        for (int j = 0; j < 4; ++j) { int r = n0 + j * 16 + lm; b[j] = *(const bf16x8*)&Bs[SWZ(r, c8)]; }
        #pragma unroll
        for (int i = 0; i < 4; ++i)
            #pragma unroll
            for (int j = 0; j < 4; ++j)
                acc[i][j] = __builtin_amdgcn_mfma_f32_16x16x32_bf16(a[i], b[j], acc[i][j], 0, 0, 0);
    }

    #pragma unroll
    for (int j = 0; j < 4; ++j) {
        float bb = bias[g * CH + n0 + j * 16 + lm];
        #pragma unroll
        for (int i = 0; i < 4; ++i)
            #pragma unroll
            for (int r = 0; r < 4; ++r) {
                int rowl = m0 + i * 16 + q * 4 + r;   // C/D: row=(lane>>4)*4+reg
                int col  = n0 + j * 16 + lm;          //      col=lane&15
                out[(row0 + rowl) * GC + g * CH + col] = f2bf(fmaxf(acc[i][j][r] + bb, 0.f));
            }
    }
}

// ---------- 7. GEMM2 (fused): Sb = dis .* (h0x@Wx1 + h0h@Wh1) -> bf16 [NP,512] ----------
__global__ __launch_bounds__(256) void k_gemm2(
        const unsigned short* __restrict__ A1, const unsigned short* __restrict__ A2,
        const unsigned short* __restrict__ Wt1, const unsigned short* __restrict__ Wt2,
        const float* __restrict__ dis, unsigned short* __restrict__ outS) {
    __shared__ uint4 As[2048];
    __shared__ uint4 Bs[2048];
    const int    g    = blockIdx.y;
    const size_t row0 = (size_t)blockIdx.x * 128;
    const int    t    = threadIdx.x;
    const int wid = t >> 6, l = t & 63;
    const int m0 = (wid >> 1) * 64, n0 = (wid & 1) * 64;
    const int lm = l & 15, q = l >> 4;
    f32x4 acc[4][4];
    #pragma unroll
    for (int i = 0; i < 4; ++i)
        #pragma unroll
        for (int j = 0; j < 4; ++j) { acc[i][j][0]=0.f; acc[i][j][1]=0.f; acc[i][j][2]=0.f; acc[i][j][3]=0.f; }

    for (int side = 0; side < 2; ++side) {
        if (side) __syncthreads();                   // all waves done reading LDS
        const unsigned short* Ap = side ? A2 : A1;
        const unsigned short* Wg = (side ? Wt2 : Wt1) + (size_t)g * 16384;
        #pragma unroll
        for (int p = 0; p < 8; ++p) {
            int id = t + 256 * p, r = id >> 4, c8 = id & 15;
            As[SWZ(r, c8)] = *(const uint4*)(Ap + (row0 + r) * GC + g * CH + c8 * 8);
        }
        #pragma unroll
        for (int p = 0; p < 8; ++p) {
            int id = t + 256 * p, r = id >> 4, c8 = id & 15;
            Bs[SWZ(r, c8)] = *(const uint4*)(Wg + r * CH + c8 * 8);
        }
        __syncthreads();
        #pragma unroll
        for (int kc = 0; kc < 4; ++kc) {
            int c8 = kc * 4 + q;
            bf16x8 a[4], b[4];
            #pragma unroll
            for (int i = 0; i < 4; ++i) { int r = m0 + i * 16 + lm; a[i] = *(const bf16x8*)&As[SWZ(r, c8)]; }
            #pragma unroll
            for (int j = 0; j < 4; ++j) { int r = n0 + j * 16 + lm; b[j] = *(const bf16x8*)&Bs[SWZ(r, c8)]; }
            #pragma unroll
            for (int i = 0; i < 4; ++i)
                #pragma unroll
                for (int j = 0; j < 4; ++j)
                    acc[i][j] = __builtin_amdgcn_mfma_f32_16x16x32_bf16(a[i], b[j], acc[i][j], 0, 0, 0);
        }
    }

    #pragma unroll
    for (int j = 0; j < 4; ++j)
        #pragma unroll
        for (int i = 0; i < 4; ++i)
            #pragma unroll
            for (int r = 0; r < 4; ++r) {
                int rowl = m0 + i * 16 + q * 4 + r;
                int col  = n0 + j * 16 + lm;
                float dr = dis[row0 + rowl];         // pre-scale for prop512g
                outS[(row0 + rowl) * GC + g * CH + col] = f2bf(dr * acc[i][j][r]);
            }
}

// ---------- 8. prop over 512-wide pre-scaled bf16 + FUSED LSTM gates ----------
// G[w] = dis_w*(sum w_e*Sb[s] + Sb[w]); then gate math via padded LDS transpose.
#define GIDX(f) ((f) + ((f) >> 5))                  // +1 float pad per 32 -> conflict-free
__global__ __launch_bounds__(256) void k_prop512g(
        const unsigned short* __restrict__ Sb, float* __restrict__ out,
        const int* __restrict__ rowoff, const int* __restrict__ csrs,
        const float* __restrict__ csrw, const float* __restrict__ dis,
        const float* __restrict__ c, const float* __restrict__ btot,
        const float* __restrict__ wc) {
    __shared__ float gbuf[4][528];                   // 8.25 KB
    int wid  = threadIdx.x >> 6, lane = threadIdx.x & 63;
    int w    = blockIdx.x * 4 + wid;                 // grid exact: NN/4 blocks
    const uint4* S4 = (const uint4*)Sb;              // row = 64 uint4 = 1 KB
    float acc[8], va[8], vb[8], vc4[8], vd[8];
    uint4 v = S4[(size_t)w * 64 + lane];
    unpack8(v, acc);                                 // self term (pre-scaled table)
    int e = rowoff[w], e1 = rowoff[w + 1];
    for (; e + 4 <= e1; e += 4) {
        int   s0 = csrs[e],   s1 = csrs[e+1], s2 = csrs[e+2], s3 = csrs[e+3];
        float n0 = csrw[e],   n1 = csrw[e+1], n2 = csrw[e+2], n3 = csrw[e+3];
        uint4 u0 = S4[(size_t)s0 * 64 + lane];
        uint4 u1 = S4[(size_t)s1 * 64 + lane];
        uint4 u2 = S4[(size_t)s2 * 64 + lane];
        uint4 u3 = S4[(size_t)s3 * 64 + lane];
        unpack8(u0, va); unpack8(u1, vb); unpack8(u2, vc4); unpack8(u3, vd);
        #pragma unroll
        for (int j = 0; j < 8; ++j)
            acc[j] += n0 * va[j] + n1 * vb[j] + n2 * vc4[j] + n3 * vd[j];
    }
    for (; e < e1; ++e) {
        int s = csrs[e]; float nw = csrw[e];
        v = S4[(size_t)s * 64 + lane];
        unpack8(v, va);
        #pragma unroll
        for (int j = 0; j < 8; ++j) acc[j] += nw * va[j];
    }
    float dw = dis[w];
    #pragma unroll
    for (int j = 0; j < 8; ++j) {
        int f = lane * 8 + j;
        gbuf[wid][GIDX(f)] = dw * acc[j];            // G (pre-bias) into LDS
    }
    __syncthreads();
    const float* gb = gbuf[wid];
    #pragma unroll
    for (int t2 = 0; t2 < 2; ++t2) {
        int hh = lane + 64 * t2;
        float g0 = gb[GIDX(hh)]       + btot[hh];
        float g1 = gb[GIDX(128 + hh)] + btot[128 + hh];
        float g2 = gb[GIDX(256 + hh)] + btot[256 + hh];
        float g3 = gb[GIDX(384 + hh)] + btot[384 + hh];
        float cv = c[(size_t)w * CH + hh];
        float I  = 1.f / (1.f + expf(-(g0 + wc[hh]       * cv)));
        float F  = 1.f / (1.f + expf(-(g1 + wc[128 + hh] * cv)));
        float T  = tanhf(g2);
        float Cn = F * cv + I * T;
        float O  = 1.f / (1.f + expf(-(g3 + wc[256 + hh] * Cn)));
        out[(size_t)w * CH + hh]         = O * tanhf(Cn);   // Hn
        out[NHtot + (size_t)w * CH + hh] = Cn;              // Cn
    }
}

extern "C" void kernel_launch(void* const* d_in, const int* in_sizes, int n_in,
                              void* d_out, int out_size, void* d_ws, size_t ws_size,
                              hipStream_t stream) {
    (void)in_sizes; (void)n_in; (void)out_size; (void)ws_size;
    const float* x   = (const float*)d_in[0];
    const int*   ei  = (const int*)d_in[1];
    const float* ew  = (const float*)d_in[2];
    const float* h   = (const float*)d_in[3];
    const float* c   = (const float*)d_in[4];
    const float* Wx0 = (const float*)d_in[5];
    const float* bx0 = (const float*)d_in[6];
    const float* Wx1 = (const float*)d_in[7];
    const float* bx1 = (const float*)d_in[8];
    const float* Wh0 = (const float*)d_in[9];
    const float* bh0 = (const float*)d_in[10];
    const float* Wh1 = (const float*)d_in[11];
    const float* bh1 = (const float*)d_in[12];
    const float* wc  = (const float*)d_in[13];
    const float* bg  = (const float*)d_in[14];
    float* out = (float*)d_out;

    // Workspace layout (float units). Each Wt* is [4][128][128] bf16 = 32768 floats.
    // (R5 bug: Wt spacing was 16384 -> overlap. Fixed: 32768.)
    float* wsf  = (float*)d_ws;
    float* dis  = wsf;                                  // [20480]
    int*   cnt  = (int*)(wsf + 20480);                  // [20480]
    int*   row  = (int*)(wsf + 40960);                  // [20736]
    int*   cur  = (int*)(wsf + 61696);                  // [20480]
    int*   bsum = (int*)(wsf + 82176);                  // [256]
    float* btot = wsf + 82432;                          // [512]
    int*   csrs = (int*)(wsf + 82944);                  // [E]
    float* csrw = wsf + 402944;                         // [E] raw weights
    unsigned short* Wt0x = (unsigned short*)(wsf + 722944);   // +32768 floats each
    unsigned short* Wt0h = (unsigned short*)(wsf + 755712);
    unsigned short* Wt1x = (unsigned short*)(wsf + 788480);
    unsigned short* Wt1h = (unsigned short*)(wsf + 821248);
    unsigned short* xhb  = (unsigned short*)(wsf + 854016);   // [NP*256] bf16 = 2572288 fl
    unsigned short* axh  = (unsigned short*)(wsf + 3426304);  // [NP*256] bf16
    unsigned short* h0x  = (unsigned short*)(wsf + 5998592);  // [NP*512] bf16 = 5144576 fl
    unsigned short* h0h  = (unsigned short*)(wsf + 11143168); // [NP*512] bf16
    unsigned short* Sb   = (unsigned short*)(wsf + 16287744); // [NP*512] bf16 (end 21432320)

    hipMemsetAsync(cnt, 0, 20480 * sizeof(int), stream);

    k_count  <<<EE / 256, 256, 0, stream>>>(ei, cnt);
    k_scan1  <<<80, 256, 0, stream>>>(cnt, row, bsum);
    k_scan2  <<<1, 64, 0, stream>>>(bsum);
    k_scan3  <<<80, 256, 0, stream>>>(row, bsum, cur);
    k_scatter<<<EE / 256, 256, 0, stream>>>(ei, ew, cur, csrs, csrw);
    k_deg    <<<(NN + 255) / 256, 256, 0, stream>>>(row, csrw, dis);

    dim3 pw(64, 4, 4);
    k_prepw  <<<pw, 256, 0, stream>>>(Wx0, Wh0, Wx1, Wh1, Wt0x, Wt0h, Wt1x, Wt1h);
    k_prepb  <<<2, 256, 0, stream>>>(bx1, bh1, bg, btot);
    k_castxh <<<NN * 32 / 256, 256, 0, stream>>>(x, h, dis, xhb);

    k_prop256<<<NN / 4, 256, 0, stream>>>(xhb, axh, row, csrs, csrw, dis);

    dim3 g1(NP / 128, 4, 2);
    k_gemm1<<<g1, 256, 0, stream>>>(axh, Wt0x, Wt0h, bx0, bh0, h0x, h0h);
    dim3 g2(NP / 128, 4);
    k_gemm2<<<g2, 256, 0, stream>>>(h0x, h0h, Wt1x, Wt1h, dis, Sb);

    k_prop512g<<<NN / 4, 256, 0, stream>>>(Sb, out, row, csrs, csrw, dis, c, btot, wc);
}